// Round 17
// baseline (631.421 us; speedup 1.0000x reference)
//
#include <hip/hip_runtime.h>

// ---------------------------------------------------------------------------
// Transformer encoder (B=2, S=2048, D=512, H=8, DK=64, DFF=2048, L=6), fp16
// MFMA compute.
// R17: extend the twin-partial split-K pattern (R12's win): W2 SK=4, WO SK=2,
// all partials merged in the following lnf (NO atomics). Layer-0 LN fused
// into embed_k (one wave per row already). attn/GEMM cores = R16 (best).
// ---------------------------------------------------------------------------

typedef _Float16 f16;
typedef _Float16 f16x8 __attribute__((ext_vector_type(8)));
typedef _Float16 f16x4 __attribute__((ext_vector_type(4)));
typedef float    f32x4 __attribute__((ext_vector_type(4)));

#define MFMA16(a, b, c) __builtin_amdgcn_mfma_f32_16x16x32_f16((a), (b), (c), 0, 0, 0)
#define GLOAD_LDS16(GP, LP)                                        \
  __builtin_amdgcn_global_load_lds(                                \
      (const __attribute__((address_space(1))) void*)(GP),         \
      (__attribute__((address_space(3))) void*)(LP), 16, 0, 0)

__device__ inline float fast_exp2(float x) {
#if __has_builtin(__builtin_amdgcn_exp2f)
  return __builtin_amdgcn_exp2f(x);
#else
  return exp2f(x);
#endif
}

static constexpr int Dm  = 512;
static constexpr int Sx  = 2048;
static constexpr int NTOK = 4096;   // B*S
static constexpr int DFFm = 2048;
static constexpr int Lc  = 6;

// ---------------------------------------------------------------- transpose+cvt
__global__ __launch_bounds__(256) void transpose_all(
    const float* __restrict__ WQ, const float* __restrict__ WK,
    const float* __restrict__ WV, const float* __restrict__ WO,
    const float* __restrict__ W1, const float* __restrict__ W2,
    f16* __restrict__ wqkv, f16* __restrict__ wtO,
    f16* __restrict__ wt1, f16* __restrict__ wt2)
{
  __shared__ float t[32][33];
  const size_t DD = (size_t)Dm * Dm;
  const size_t DQKV = (size_t)1536 * Dm;
  const size_t DF = (size_t)Dm * DFFm;
  int id = blockIdx.x;
  const float* src; f16* dst; int R, C, bx, by;
  if (id < 6144) {
    const int z = id >> 8, rem = id & 255;
    bx = rem & 15; by = rem >> 4;
    const int widx = z / 6, layer = z % 6;
    src = ((widx == 0) ? WQ : (widx == 1) ? WK : (widx == 2) ? WV : WO)
          + (size_t)layer * DD;
    dst = (widx < 3) ? wqkv + (size_t)layer * DQKV + (size_t)widx * 512 * Dm
                     : wtO + (size_t)layer * DD;
    R = 512; C = 512;
  } else if (id < 12288) {
    id -= 6144;
    const int layer = id >> 10, rem = id & 1023;
    bx = rem & 63; by = rem >> 6;
    src = W1 + (size_t)layer * DF;
    dst = wt1 + (size_t)layer * DF;
    R = 512; C = 2048;
  } else {
    id -= 12288;
    const int layer = id >> 10, rem = id & 1023;
    bx = rem & 15; by = rem >> 4;
    src = W2 + (size_t)layer * DF;
    dst = wt2 + (size_t)layer * DF;
    R = 2048; C = 512;
  }
  const int r0 = by * 32, c0 = bx * 32;
  const int tx = threadIdx.x, ty = threadIdx.y;
  #pragma unroll
  for (int i = 0; i < 4; i++)
    t[ty + i * 8][tx] = src[(size_t)(r0 + ty + i * 8) * C + c0 + tx];
  __syncthreads();
  #pragma unroll
  for (int i = 0; i < 4; i++)
    dst[(size_t)(c0 + ty + i * 8) * R + r0 + tx] = (f16)t[tx][ty + i * 8];
}

// ---------------------------------------------------------------- embedding
// One wave per token row: emb+pe -> x (f16), mask, then layer-0 ln1 -> hbuf.
__global__ __launch_bounds__(256) void embed_k(
    const int* __restrict__ src, const float* __restrict__ emb,
    const float* __restrict__ pe, const float* __restrict__ sc,
    const float* __restrict__ bi, f16* __restrict__ x,
    f16* __restrict__ hbuf, float* __restrict__ mb)
{
  const int row = blockIdx.x * 4 + (threadIdx.x >> 6);
  const int l = threadIdx.x & 63;
  const int s = row & (Sx - 1);
  const int tk = src[row];
  if (l == 0) mb[row] = (tk != 0) ? 0.f : -3.0e38f;
  const float* e = emb + (size_t)tk * Dm + l * 8;
  const float* p = pe + (size_t)s * Dm + l * 8;
  const float SC = 22.627416997969522f;  // sqrt(512)
  float v[8];
  f16x8 xo;
  #pragma unroll
  for (int j = 0; j < 8; j++) {
    v[j] = e[j] * SC + p[j];
    xo[j] = (f16)v[j];
    v[j] = (float)xo[j];           // match f16 residual numerics
  }
  *(f16x8*)(x + (size_t)row * Dm + l * 8) = xo;
  float ss = 0.f;
  #pragma unroll
  for (int j = 0; j < 8; j++) ss += v[j];
  #pragma unroll
  for (int m = 1; m < 64; m <<= 1) ss += __shfl_xor(ss, m);
  const float mu = ss * (1.0f / 512.0f);
  float qv = 0.f;
  #pragma unroll
  for (int j = 0; j < 8; j++) { float d = v[j] - mu; qv += d * d; }
  #pragma unroll
  for (int m = 1; m < 64; m <<= 1) qv += __shfl_xor(qv, m);
  const float inv = rsqrtf(qv * (1.0f / 512.0f) + 1e-5f);
  float scv[8], biv[8];
  *(float4*)&scv[0] = *(const float4*)(sc + l * 8);
  *(float4*)&scv[4] = *(const float4*)(sc + l * 8 + 4);
  *(float4*)&biv[0] = *(const float4*)(bi + l * 8);
  *(float4*)&biv[4] = *(const float4*)(bi + l * 8 + 4);
  f16x8 o;
  #pragma unroll
  for (int j = 0; j < 8; j++) o[j] = (f16)((v[j] - mu) * inv * scv[j] + biv[j]);
  *(f16x8*)(hbuf + (size_t)row * Dm + l * 8) = o;
}

// ---------------------------------------------------------------- fused LN
// x f16; sum NP partial buffers (stride NTOK*Dm) + optional bias; f32 accum.
template <typename OUT, int NP, int BIAS, int WRITEX>
__global__ __launch_bounds__(256) void lnf_k(
    const f16* __restrict__ x, const f16* __restrict__ part,
    const float* __restrict__ bias,
    const float* __restrict__ sc, const float* __restrict__ bi,
    OUT* __restrict__ out, f16* __restrict__ xout)
{
  const int row = blockIdx.x * 4 + (threadIdx.x >> 6);
  const int l = threadIdx.x & 63;
  f16x8 xv = *(const f16x8*)(x + (size_t)row * Dm + l * 8);
  float v[8];
  #pragma unroll
  for (int j = 0; j < 8; j++) v[j] = (float)xv[j];
  if constexpr (NP >= 1) {
    #pragma unroll
    for (int i = 0; i < NP; i++) {
      f16x8 p = *(const f16x8*)(part + (size_t)i * NTOK * Dm + (size_t)row * Dm + l * 8);
      #pragma unroll
      for (int j = 0; j < 8; j++) v[j] += (float)p[j];
    }
    if constexpr (BIAS) {
      float bb[8];
      *(float4*)&bb[0] = *(const float4*)(bias + l * 8);
      *(float4*)&bb[4] = *(const float4*)(bias + l * 8 + 4);
      #pragma unroll
      for (int j = 0; j < 8; j++) v[j] += bb[j];
    }
    if constexpr (WRITEX) {
      f16x8 xo;
      #pragma unroll
      for (int j = 0; j < 8; j++) xo[j] = (f16)v[j];
      *(f16x8*)(xout + (size_t)row * Dm + l * 8) = xo;
    }
  }
  float s = 0.f;
  #pragma unroll
  for (int j = 0; j < 8; j++) s += v[j];
  #pragma unroll
  for (int m = 1; m < 64; m <<= 1) s += __shfl_xor(s, m);
  const float mu = s * (1.0f / 512.0f);
  float qv = 0.f;
  #pragma unroll
  for (int j = 0; j < 8; j++) { float d = v[j] - mu; qv += d * d; }
  #pragma unroll
  for (int m = 1; m < 64; m <<= 1) qv += __shfl_xor(qv, m);
  const float inv = rsqrtf(qv * (1.0f / 512.0f) + 1e-5f);
  float scv[8], biv[8];
  *(float4*)&scv[0] = *(const float4*)(sc + l * 8);
  *(float4*)&scv[4] = *(const float4*)(sc + l * 8 + 4);
  *(float4*)&biv[0] = *(const float4*)(bi + l * 8);
  *(float4*)&biv[4] = *(const float4*)(bi + l * 8 + 4);
  if constexpr (sizeof(OUT) == 2) {
    f16x8 o;
    #pragma unroll
    for (int j = 0; j < 8; j++) o[j] = (f16)((v[j] - mu) * inv * scv[j] + biv[j]);
    *(f16x8*)((f16*)out + (size_t)row * Dm + l * 8) = o;
  } else {
    float o[8];
    #pragma unroll
    for (int j = 0; j < 8; j++) o[j] = (v[j] - mu) * inv * scv[j] + biv[j];
    float* po = (float*)out + (size_t)row * Dm + l * 8;
    *(float4*)po = *(float4*)&o[0];
    *(float4*)(po + 4) = *(float4*)&o[4];
  }
}

// ---------------------------------------------------------------- GEMM
// MODE 0: fused QKV (Q->O0, K->O1, sigma-permuted V^T->O2)
// MODE 1: O0 = acc | MODE 2: O0 = relu(acc+bias)
// MODE 3: split-K partial (f16) -> O0 + ks*NTOK*N, merged in next lnf
template <int BN, int MODE, int N, int K, int SK>
__global__ __launch_bounds__(256) void gemm_k(
    const f16* __restrict__ A, const f16* __restrict__ Bt,
    f16* __restrict__ O0, f16* __restrict__ O1, f16* __restrict__ O2,
    const float* __restrict__ bias)
{
  constexpr int BM = 128;
  constexpr int NF = (BN >= 32) ? BN / 32 : 1;
  constexpr int NBM = NTOK / BM;            // 32
  constexpr int NBN = N / BN;
  constexpr int NB = NBM * NBN * SK;
  __shared__ f16 lsA[2][BM * 64];
  __shared__ f16 lsB[2][BN * 64];
  const int tid = threadIdx.x;
  const int l = tid & 63, w = tid >> 6;
  const int lr = l & 15, lh = l >> 4;
  const int wm = w >> 1, wn = w & 1;
  const int bid = blockIdx.x;
  const int nid = (bid & 7) * (NB / 8) + (bid >> 3);
  const int ks = nid / (NBM * NBN);
  const int rr = nid % (NBM * NBN);
  const int bm = rr / NBN, bn = rr % NBN;

  constexpr int ACH = (BM * 64) / (256 * 8);
  constexpr int BCH = (BN * 64) / (256 * 8);
  const size_t rowA0 = (size_t)bm * BM;
  const size_t rowB0 = (size_t)bn * BN;
  const int k0 = ks * (K / SK);

  auto stage = [&](int kt, int pb) {
    #pragma unroll
    for (int i = 0; i < ACH; i++) {
      int c = i * 256 + tid, r = c >> 3, g = c & 7, gs = g ^ (r & 7);
      GLOAD_LDS16(A + (rowA0 + r) * K + k0 + kt * 64 + gs * 8, &lsA[pb][c * 8]);
    }
    #pragma unroll
    for (int i = 0; i < BCH; i++) {
      int c = i * 256 + tid, r = c >> 3, g = c & 7, gs = g ^ (r & 7);
      GLOAD_LDS16(Bt + (rowB0 + r) * K + k0 + kt * 64 + gs * 8, &lsB[pb][c * 8]);
    }
  };

  f32x4 acc[4][NF] = {};
  stage(0, 0);
  constexpr int NT = (K / SK) >> 6;
  for (int kt = 0; kt < NT; ++kt) {
    const int cur = kt & 1;
    __syncthreads();
    if (kt + 1 < NT) stage(kt + 1, cur ^ 1);
    #pragma unroll
    for (int s = 0; s < 2; s++) {
      const int gg = (s * 4 + lh) ^ (lr & 7);
      f16x8 af[4], bf[NF];
      #pragma unroll
      for (int mf = 0; mf < 4; mf++)
        af[mf] = *(const f16x8*)(&lsA[cur][(wm * 64 + mf * 16 + lr) * 64 + gg * 8]);
      #pragma unroll
      for (int nf = 0; nf < NF; nf++)
        bf[nf] = *(const f16x8*)(&lsB[cur][(wn * (BN / 2) + nf * 16 + lr) * 64 + gg * 8]);
      #pragma unroll
      for (int mf = 0; mf < 4; mf++)
        #pragma unroll
        for (int nf = 0; nf < NF; nf++)
          acc[mf][nf] = MFMA16(af[mf], bf[nf], acc[mf][nf]);
    }
  }

  #pragma unroll
  for (int mf = 0; mf < 4; mf++) {
    #pragma unroll
    for (int nf = 0; nf < NF; nf++) {
      const int token = bm * BM + wm * 64 + mf * 16 + lh * 4;
      const int ch = bn * BN + wn * (BN / 2) + nf * 16 + lr;
      if constexpr (MODE == 0) {
        const int part = ch >> 9;          // 0=Q 1=K 2=V
        const int pch = ch & 511;
        if (part == 2) {
          f16x4 o;
          #pragma unroll
          for (int r = 0; r < 4; r++) o[r] = (f16)acc[mf][nf][r];
          const int bb = token >> 11, ss = token & (Sx - 1);
          const int scol = (ss & ~31) | (((ss >> 2) & 3) << 3) | (((ss >> 4) & 1) << 2);
          *(f16x4*)(O2 + ((size_t)((bb << 3) + (pch >> 6)) * 64 + (pch & 63)) * Sx + scol) = o;
        } else {
          f16* Oz = (part == 0) ? O0 : O1;
          #pragma unroll
          for (int r = 0; r < 4; r++)
            Oz[(size_t)(token + r) * Dm + pch] = (f16)acc[mf][nf][r];
        }
      } else if constexpr (MODE == 1) {
        #pragma unroll
        for (int r = 0; r < 4; r++)
          O0[(size_t)(token + r) * N + ch] = (f16)acc[mf][nf][r];
      } else if constexpr (MODE == 2) {
        #pragma unroll
        for (int r = 0; r < 4; r++) {
          float v = acc[mf][nf][r] + bias[ch];
          O0[(size_t)(token + r) * N + ch] = (f16)fmaxf(v, 0.f);
        }
      } else {
        f16* dst = O0 + (size_t)ks * NTOK * N;
        #pragma unroll
        for (int r = 0; r < 4; r++)
          dst[(size_t)(token + r) * N + ch] = (f16)acc[mf][nf][r];
      }
    }
  }
}

// ---------------------------------------------------------------- attention
// (R16 = best) Flash split-K, exp2 domain. 8 waves; grp = w>>2 handles 1024
// keys in 16 dbuf 64-key tiles (1 barrier/tile); 16 q/wave; 2-way LDS merge
// with 20-f32 slot stride. K/V XOR-swizzled via pre-swizzled global src;
// mask = MFMA C-init; row-sum via MFMA ones-trick; sigma-permuted V^T.
__global__ __launch_bounds__(512) void attn_k(
    const f16* __restrict__ q, const f16* __restrict__ kk,
    const f16* __restrict__ vt, const float* __restrict__ maskb,
    f16* __restrict__ out)
{
  __shared__ f16 lsK[2][2][64 * 64];   // [grp][dbuf]
  __shared__ f16 lsV[2][2][64 * 64];
  const int tid = threadIdx.x;
  const int l = tid & 63, w = tid >> 6;
  const int lr = l & 15, lh = l >> 4;
  const int grp = w >> 2;
  const int t256 = tid & 255;
  const int bid = blockIdx.x;
  const int nid = ((bid & 7) << 6) + (bid >> 3);   // NB=512, chunk 64
  const int bh = nid >> 5;                          // 0..15
  const int qt = nid & 31;                          // 0..31
  const int b = bh >> 3, h = bh & 7;

  const _Float16 QS = (_Float16)0.18033688f;
  f16x8 qf[2];
  #pragma unroll
  for (int s = 0; s < 2; s++) {
    size_t row = (size_t)(b * Sx + qt * 64 + (w & 3) * 16 + lr);
    f16x8 t = *(const f16x8*)(q + row * Dm + h * 64 + s * 32 + lh * 8);
    qf[s] = t * QS;
  }

  const f16x8 ones = {(f16)1, (f16)1, (f16)1, (f16)1,
                      (f16)1, (f16)1, (f16)1, (f16)1};
  f32x4 oacc[4] = {};
  f32x4 sumacc = {};
  float mrun = -1e30f;

  auto stage = [&](int t, int pb) {
    #pragma unroll
    for (int i = 0; i < 2; i++) {
      int c = i * 256 + t256, r = c >> 3, g = c & 7, gs = g ^ (r & 7);
      GLOAD_LDS16(kk + (size_t)(b * Sx + t * 64 + r) * Dm + h * 64 + gs * 8,
                  &lsK[grp][pb][c * 8]);
      GLOAD_LDS16(vt + (size_t)(bh * 64 + r) * Sx + t * 64 + gs * 8,
                  &lsV[grp][pb][c * 8]);
    }
  };
  stage(grp * 16, 0);

  for (int i = 0; i < 16; ++i) {
    const int t = grp * 16 + i;
    const int cur = i & 1;
    __syncthreads();               // vmcnt(0) drain: buf[cur] ready
    if (i < 15) stage(t + 1, cur ^ 1);

    f32x4 sacc[4];
    #pragma unroll
    for (int kf = 0; kf < 4; kf++)
      sacc[kf] = *(const f32x4*)(maskb + b * Sx + t * 64 + kf * 16 + lh * 4);
    __builtin_amdgcn_s_setprio(1);
    #pragma unroll
    for (int s = 0; s < 2; s++) {
      const int gk = (s * 4 + lh) ^ (lr & 7);
      #pragma unroll
      for (int kf = 0; kf < 4; kf++) {
        f16x8 a = *(const f16x8*)(&lsK[grp][cur][(kf * 16 + lr) * 64 + gk * 8]);
        sacc[kf] = MFMA16(a, qf[s], sacc[kf]);
      }
    }
    __builtin_amdgcn_s_setprio(0);

    float pmax;
    {
      float t0 = fmaxf(fmaxf(sacc[0][0], sacc[0][1]), sacc[0][2]);
      float t1 = fmaxf(fmaxf(sacc[0][3], sacc[1][0]), sacc[1][1]);
      float t2 = fmaxf(fmaxf(sacc[1][2], sacc[1][3]), sacc[2][0]);
      float t3 = fmaxf(fmaxf(sacc[2][1], sacc[2][2]), sacc[2][3]);
      float t4 = fmaxf(fmaxf(sacc[3][0], sacc[3][1]), sacc[3][2]);
      float u0 = fmaxf(fmaxf(t0, t1), sacc[3][3]);
      float u1 = fmaxf(fmaxf(t2, t3), t4);
      pmax = fmaxf(u0, u1);
    }
    pmax = fmaxf(pmax, __shfl_xor(pmax, 16));
    pmax = fmaxf(pmax, __shfl_xor(pmax, 32));
    if (!__all(pmax - mrun <= 8.0f)) {       // defer-max (T13)
      const float mnew = fmaxf(mrun, pmax);
      const float rs = fast_exp2(mrun - mnew);
      sumacc *= rs;
      #pragma unroll
      for (int mf = 0; mf < 4; mf++) oacc[mf] *= rs;
      mrun = mnew;
    }
    #pragma unroll
    for (int kf = 0; kf < 4; kf++)
      #pragma unroll
      for (int r = 0; r < 4; r++)
        sacc[kf][r] = fast_exp2(sacc[kf][r] - mrun);
    f16x8 pa[2];
    #pragma unroll
    for (int s = 0; s < 2; s++)
      #pragma unroll
      for (int jj = 0; jj < 8; jj++)
        pa[s][jj] = (f16)sacc[2 * s + (jj >> 2)][jj & 3];
    sumacc = MFMA16(ones, pa[0], sumacc);
    sumacc = MFMA16(ones, pa[1], sumacc);

    __builtin_amdgcn_s_setprio(1);
    #pragma unroll
    for (int s = 0; s < 2; s++) {
      const int gv = (4 * s + lh) ^ (lr & 7);
      #pragma unroll
      for (int mf = 0; mf < 4; mf++) {
        f16x8 vv = *(const f16x8*)(&lsV[grp][cur][(mf * 16 + lr) * 64 + gv * 8]);
        oacc[mf] = MFMA16(vv, pa[s], oacc[mf]);
      }
    }
    __builtin_amdgcn_s_setprio(0);
  }

  const float lrun = sumacc[0];
  __syncthreads();
  float* sO  = (float*)&lsK[0][0][0];     // 256 slots * 20 f32
  float* sML = (float*)&lsV[0][0][0];
  const int wl = (w & 3) * 64 + l;
  if (grp == 1) {
    #pragma unroll
    for (int mf = 0; mf < 4; mf++)
      #pragma unroll
      for (int r = 0; r < 4; r++) sO[wl * 20 + mf * 4 + r] = oacc[mf][r];
    sML[wl * 2] = mrun;
    sML[wl * 2 + 1] = lrun;
  }
  __syncthreads();
  if (grp == 0) {
    const float m1 = sML[wl * 2], l1 = sML[wl * 2 + 1];
    const float mm = fmaxf(mrun, m1);
    const float s0 = fast_exp2(mrun - mm), s1 = fast_exp2(m1 - mm);
    const float inv = 1.f / (lrun * s0 + l1 * s1);
    size_t row = (size_t)(b * Sx + qt * 64 + (w & 3) * 16 + lr);
    #pragma unroll
    for (int mf = 0; mf < 4; mf++) {
      f16x4 o;
      #pragma unroll
      for (int r = 0; r < 4; r++)
        o[r] = (f16)((oacc[mf][r] * s0 + sO[wl * 20 + mf * 4 + r] * s1) * inv);
      *(f16x4*)(out + row * Dm + h * 64 + mf * 16 + lh * 4) = o;
    }
  }
}

// ---------------------------------------------------------------- launch
extern "C" void kernel_launch(void* const* d_in, const int* in_sizes, int n_in,
                              void* d_out, int out_size, void* d_ws, size_t ws_size,
                              hipStream_t stream)
{
  (void)in_sizes; (void)n_in; (void)out_size; (void)ws_size;
  const int*   src  = (const int*)d_in[0];
  const float* emb  = (const float*)d_in[1];
  const float* pe   = (const float*)d_in[2];
  const float* WQ   = (const float*)d_in[3];
  const float* WK   = (const float*)d_in[4];
  const float* WV   = (const float*)d_in[5];
  const float* WO   = (const float*)d_in[6];
  const float* W1   = (const float*)d_in[7];
  const float* b1   = (const float*)d_in[8];
  const float* W2   = (const float*)d_in[9];
  const float* b2   = (const float*)d_in[10];
  const float* ln1s = (const float*)d_in[11];
  const float* ln1b = (const float*)d_in[12];
  const float* ln2s = (const float*)d_in[13];
  const float* ln2b = (const float*)d_in[14];
  const float* fns  = (const float*)d_in[15];
  const float* fnb  = (const float*)d_in[16];

  char* ws = (char*)d_ws;
  const size_t DD = (size_t)Dm * Dm;
  const size_t DQKV = (size_t)1536 * Dm;
  const size_t DF = (size_t)Dm * DFFm;
  f16* wqkv = (f16*)(ws);                      // [L][1536][512]
  f16* wtO  = wqkv + Lc * DQKV;                // [L][512][512]
  f16* wt1  = wtO + Lc * DD;                   // [L][2048][512]
  f16* wt2  = wt1 + Lc * DF;                   // [L][512][2048]
  f16* x    = wt2 + Lc * DF;                   // [4096][512] f16 residual
  f16* hbuf = x + (size_t)NTOK * Dm;
  f16* qb   = hbuf + (size_t)NTOK * Dm;
  f16* kb   = qb + (size_t)NTOK * Dm;
  f16* vtb  = kb + (size_t)NTOK * Dm;          // [16][64][2048] sigma-permuted V^T
  f16* attn = vtb + (size_t)NTOK * Dm;
  f16* aout = attn + (size_t)NTOK * Dm;        // WO partials [2][4096][512]
  f16* ff   = aout + (size_t)2 * NTOK * Dm;    // [4096][2048]
  f16* ffo  = ff + (size_t)NTOK * DFFm;        // W2 partials [4][4096][512]
  float* maskb = (float*)(ffo + (size_t)4 * NTOK * Dm);

  transpose_all<<<18432, dim3(32, 8), 0, stream>>>(
      WQ, WK, WV, WO, W1, W2, wqkv, wtO, wt1, wt2);
  embed_k<<<1024, 256, 0, stream>>>(src, emb, pe, ln1s, ln1b, x, hbuf, maskb);

  for (int l = 0; l < Lc; l++) {
    const f16* wqkv_l = wqkv + (size_t)l * DQKV;
    const f16* wo = wtO + (size_t)l * DD;
    const f16* w1 = wt1 + (size_t)l * DF;
    const f16* w2 = wt2 + (size_t)l * DF;

    if (l > 0)
      lnf_k<f16, 4, 1, 1><<<1024, 256, 0, stream>>>(
          x, ffo, b2 + (size_t)(l - 1) * Dm, ln1s + l * Dm, ln1b + l * Dm,
          hbuf, x);
    gemm_k<64, 0, 1536, 512, 1><<<768, 256, 0, stream>>>(
        hbuf, wqkv_l, qb, kb, vtb, nullptr);
    attn_k<<<512, 512, 0, stream>>>(qb, kb, vtb, maskb, attn);
    gemm_k<64, 3, 512, 512, 2><<<1024, 256, 0, stream>>>(
        attn, wo, aout, nullptr, nullptr, nullptr);
    lnf_k<f16, 2, 0, 1><<<1024, 256, 0, stream>>>(
        x, aout, nullptr, ln2s + l * Dm, ln2b + l * Dm, hbuf, x);
    gemm_k<128, 2, 2048, 512, 1><<<512, 256, 0, stream>>>(
        hbuf, w1, ff, nullptr, nullptr, b1 + (size_t)l * DFFm);
    gemm_k<64, 3, 512, 2048, 4><<<1024, 256, 0, stream>>>(
        ff, w2, ffo, nullptr, nullptr, nullptr);
  }

  lnf_k<float, 4, 1, 0><<<1024, 256, 0, stream>>>(
      x, ffo, b2 + (size_t)(Lc - 1) * Dm, fns, fnb, (float*)d_out, nullptr);
}

// Round 18
// 597.805 us; speedup vs baseline: 1.0562x; 1.0562x over previous
//
#include <hip/hip_runtime.h>

// ---------------------------------------------------------------------------
// Transformer encoder (B=2, S=2048, D=512, H=8, DK=64, DFF=2048, L=6), fp16
// MFMA compute.
// R18: rollback to R16 (best, 598.9us) + keep R17's one good piece: layer-0
// LN fused into embed_k. W2 stays SK=2 twin-partial; WO stays SK=1.
// (R17 lesson: split-K pays only when serial-K saved > partial traffic added;
// W2@SK4 and WO@SK2 both fail that test.)
// ---------------------------------------------------------------------------

typedef _Float16 f16;
typedef _Float16 f16x8 __attribute__((ext_vector_type(8)));
typedef _Float16 f16x4 __attribute__((ext_vector_type(4)));
typedef float    f32x4 __attribute__((ext_vector_type(4)));

#define MFMA16(a, b, c) __builtin_amdgcn_mfma_f32_16x16x32_f16((a), (b), (c), 0, 0, 0)
#define GLOAD_LDS16(GP, LP)                                        \
  __builtin_amdgcn_global_load_lds(                                \
      (const __attribute__((address_space(1))) void*)(GP),         \
      (__attribute__((address_space(3))) void*)(LP), 16, 0, 0)

__device__ inline float fast_exp2(float x) {
#if __has_builtin(__builtin_amdgcn_exp2f)
  return __builtin_amdgcn_exp2f(x);
#else
  return exp2f(x);
#endif
}

static constexpr int Dm  = 512;
static constexpr int Sx  = 2048;
static constexpr int NTOK = 4096;   // B*S
static constexpr int DFFm = 2048;
static constexpr int Lc  = 6;

// ---------------------------------------------------------------- transpose+cvt
__global__ __launch_bounds__(256) void transpose_all(
    const float* __restrict__ WQ, const float* __restrict__ WK,
    const float* __restrict__ WV, const float* __restrict__ WO,
    const float* __restrict__ W1, const float* __restrict__ W2,
    f16* __restrict__ wqkv, f16* __restrict__ wtO,
    f16* __restrict__ wt1, f16* __restrict__ wt2)
{
  __shared__ float t[32][33];
  const size_t DD = (size_t)Dm * Dm;
  const size_t DQKV = (size_t)1536 * Dm;
  const size_t DF = (size_t)Dm * DFFm;
  int id = blockIdx.x;
  const float* src; f16* dst; int R, C, bx, by;
  if (id < 6144) {
    const int z = id >> 8, rem = id & 255;
    bx = rem & 15; by = rem >> 4;
    const int widx = z / 6, layer = z % 6;
    src = ((widx == 0) ? WQ : (widx == 1) ? WK : (widx == 2) ? WV : WO)
          + (size_t)layer * DD;
    dst = (widx < 3) ? wqkv + (size_t)layer * DQKV + (size_t)widx * 512 * Dm
                     : wtO + (size_t)layer * DD;
    R = 512; C = 512;
  } else if (id < 12288) {
    id -= 6144;
    const int layer = id >> 10, rem = id & 1023;
    bx = rem & 63; by = rem >> 6;
    src = W1 + (size_t)layer * DF;
    dst = wt1 + (size_t)layer * DF;
    R = 512; C = 2048;
  } else {
    id -= 12288;
    const int layer = id >> 10, rem = id & 1023;
    bx = rem & 15; by = rem >> 4;
    src = W2 + (size_t)layer * DF;
    dst = wt2 + (size_t)layer * DF;
    R = 2048; C = 512;
  }
  const int r0 = by * 32, c0 = bx * 32;
  const int tx = threadIdx.x, ty = threadIdx.y;
  #pragma unroll
  for (int i = 0; i < 4; i++)
    t[ty + i * 8][tx] = src[(size_t)(r0 + ty + i * 8) * C + c0 + tx];
  __syncthreads();
  #pragma unroll
  for (int i = 0; i < 4; i++)
    dst[(size_t)(c0 + ty + i * 8) * R + r0 + tx] = (f16)t[tx][ty + i * 8];
}

// ---------------------------------------------------------------- embedding
// One wave per token row: emb+pe -> x (f16), mask, then layer-0 ln1 -> hbuf.
__global__ __launch_bounds__(256) void embed_k(
    const int* __restrict__ src, const float* __restrict__ emb,
    const float* __restrict__ pe, const float* __restrict__ sc,
    const float* __restrict__ bi, f16* __restrict__ x,
    f16* __restrict__ hbuf, float* __restrict__ mb)
{
  const int row = blockIdx.x * 4 + (threadIdx.x >> 6);
  const int l = threadIdx.x & 63;
  const int s = row & (Sx - 1);
  const int tk = src[row];
  if (l == 0) mb[row] = (tk != 0) ? 0.f : -3.0e38f;
  const float* e = emb + (size_t)tk * Dm + l * 8;
  const float* p = pe + (size_t)s * Dm + l * 8;
  const float SC = 22.627416997969522f;  // sqrt(512)
  float v[8];
  f16x8 xo;
  #pragma unroll
  for (int j = 0; j < 8; j++) {
    v[j] = e[j] * SC + p[j];
    xo[j] = (f16)v[j];
    v[j] = (float)xo[j];           // match f16 residual numerics
  }
  *(f16x8*)(x + (size_t)row * Dm + l * 8) = xo;
  float ss = 0.f;
  #pragma unroll
  for (int j = 0; j < 8; j++) ss += v[j];
  #pragma unroll
  for (int m = 1; m < 64; m <<= 1) ss += __shfl_xor(ss, m);
  const float mu = ss * (1.0f / 512.0f);
  float qv = 0.f;
  #pragma unroll
  for (int j = 0; j < 8; j++) { float d = v[j] - mu; qv += d * d; }
  #pragma unroll
  for (int m = 1; m < 64; m <<= 1) qv += __shfl_xor(qv, m);
  const float inv = rsqrtf(qv * (1.0f / 512.0f) + 1e-5f);
  float scv[8], biv[8];
  *(float4*)&scv[0] = *(const float4*)(sc + l * 8);
  *(float4*)&scv[4] = *(const float4*)(sc + l * 8 + 4);
  *(float4*)&biv[0] = *(const float4*)(bi + l * 8);
  *(float4*)&biv[4] = *(const float4*)(bi + l * 8 + 4);
  f16x8 o;
  #pragma unroll
  for (int j = 0; j < 8; j++) o[j] = (f16)((v[j] - mu) * inv * scv[j] + biv[j]);
  *(f16x8*)(hbuf + (size_t)row * Dm + l * 8) = o;
}

// ---------------------------------------------------------------- fused LN
// ADD=0: plain LN. ADD=1: x += part (+bias). ADD=2: x += part+part2 (+bias).
template <typename OUT, int ADD, int BIAS, int WRITEX>
__global__ __launch_bounds__(256) void lnf_k(
    const f16* __restrict__ x, const f16* __restrict__ part,
    const f16* __restrict__ part2, const float* __restrict__ bias,
    const float* __restrict__ sc, const float* __restrict__ bi,
    OUT* __restrict__ out, f16* __restrict__ xout)
{
  const int row = blockIdx.x * 4 + (threadIdx.x >> 6);
  const int l = threadIdx.x & 63;
  f16x8 xv = *(const f16x8*)(x + (size_t)row * Dm + l * 8);
  float v[8];
  #pragma unroll
  for (int j = 0; j < 8; j++) v[j] = (float)xv[j];
  if constexpr (ADD >= 1) {
    f16x8 p = *(const f16x8*)(part + (size_t)row * Dm + l * 8);
    #pragma unroll
    for (int j = 0; j < 8; j++) v[j] += (float)p[j];
    if constexpr (ADD == 2) {
      f16x8 p2 = *(const f16x8*)(part2 + (size_t)row * Dm + l * 8);
      #pragma unroll
      for (int j = 0; j < 8; j++) v[j] += (float)p2[j];
    }
    if constexpr (BIAS) {
      float bb[8];
      *(float4*)&bb[0] = *(const float4*)(bias + l * 8);
      *(float4*)&bb[4] = *(const float4*)(bias + l * 8 + 4);
      #pragma unroll
      for (int j = 0; j < 8; j++) v[j] += bb[j];
    }
    if constexpr (WRITEX) {
      f16x8 xo;
      #pragma unroll
      for (int j = 0; j < 8; j++) xo[j] = (f16)v[j];
      *(f16x8*)(xout + (size_t)row * Dm + l * 8) = xo;
    }
  }
  float s = 0.f;
  #pragma unroll
  for (int j = 0; j < 8; j++) s += v[j];
  #pragma unroll
  for (int m = 1; m < 64; m <<= 1) s += __shfl_xor(s, m);
  const float mu = s * (1.0f / 512.0f);
  float qv = 0.f;
  #pragma unroll
  for (int j = 0; j < 8; j++) { float d = v[j] - mu; qv += d * d; }
  #pragma unroll
  for (int m = 1; m < 64; m <<= 1) qv += __shfl_xor(qv, m);
  const float inv = rsqrtf(qv * (1.0f / 512.0f) + 1e-5f);
  float scv[8], biv[8];
  *(float4*)&scv[0] = *(const float4*)(sc + l * 8);
  *(float4*)&scv[4] = *(const float4*)(sc + l * 8 + 4);
  *(float4*)&biv[0] = *(const float4*)(bi + l * 8);
  *(float4*)&biv[4] = *(const float4*)(bi + l * 8 + 4);
  if constexpr (sizeof(OUT) == 2) {
    f16x8 o;
    #pragma unroll
    for (int j = 0; j < 8; j++) o[j] = (f16)((v[j] - mu) * inv * scv[j] + biv[j]);
    *(f16x8*)((f16*)out + (size_t)row * Dm + l * 8) = o;
  } else {
    float o[8];
    #pragma unroll
    for (int j = 0; j < 8; j++) o[j] = (v[j] - mu) * inv * scv[j] + biv[j];
    float* po = (float*)out + (size_t)row * Dm + l * 8;
    *(float4*)po = *(float4*)&o[0];
    *(float4*)(po + 4) = *(float4*)&o[4];
  }
}

// ---------------------------------------------------------------- GEMM
// MODE 0: fused QKV (Q->O0, K->O1, sigma-permuted V^T->O2)
// MODE 1: O0 = acc | MODE 2: O0 = relu(acc+bias) | MODE 3: split-K partials
template <int BN, int MODE, int N, int K, int SK>
__global__ __launch_bounds__(256) void gemm_k(
    const f16* __restrict__ A, const f16* __restrict__ Bt,
    f16* __restrict__ O0, f16* __restrict__ O1, f16* __restrict__ O2,
    const float* __restrict__ bias)
{
  constexpr int BM = 128;
  constexpr int NF = (BN >= 32) ? BN / 32 : 1;
  constexpr int NBM = NTOK / BM;            // 32
  constexpr int NBN = N / BN;
  constexpr int NB = NBM * NBN * SK;
  __shared__ f16 lsA[2][BM * 64];
  __shared__ f16 lsB[2][BN * 64];
  const int tid = threadIdx.x;
  const int l = tid & 63, w = tid >> 6;
  const int lr = l & 15, lh = l >> 4;
  const int wm = w >> 1, wn = w & 1;
  const int bid = blockIdx.x;
  const int nid = (bid & 7) * (NB / 8) + (bid >> 3);
  const int ks = nid / (NBM * NBN);
  const int rr = nid % (NBM * NBN);
  const int bm = rr / NBN, bn = rr % NBN;

  constexpr int ACH = (BM * 64) / (256 * 8);
  constexpr int BCH = (BN * 64) / (256 * 8);
  const size_t rowA0 = (size_t)bm * BM;
  const size_t rowB0 = (size_t)bn * BN;
  const int k0 = ks * (K / SK);

  auto stage = [&](int kt, int pb) {
    #pragma unroll
    for (int i = 0; i < ACH; i++) {
      int c = i * 256 + tid, r = c >> 3, g = c & 7, gs = g ^ (r & 7);
      GLOAD_LDS16(A + (rowA0 + r) * K + k0 + kt * 64 + gs * 8, &lsA[pb][c * 8]);
    }
    #pragma unroll
    for (int i = 0; i < BCH; i++) {
      int c = i * 256 + tid, r = c >> 3, g = c & 7, gs = g ^ (r & 7);
      GLOAD_LDS16(Bt + (rowB0 + r) * K + k0 + kt * 64 + gs * 8, &lsB[pb][c * 8]);
    }
  };

  f32x4 acc[4][NF] = {};
  stage(0, 0);
  constexpr int NT = (K / SK) >> 6;
  for (int kt = 0; kt < NT; ++kt) {
    const int cur = kt & 1;
    __syncthreads();
    if (kt + 1 < NT) stage(kt + 1, cur ^ 1);
    #pragma unroll
    for (int s = 0; s < 2; s++) {
      const int gg = (s * 4 + lh) ^ (lr & 7);
      f16x8 af[4], bf[NF];
      #pragma unroll
      for (int mf = 0; mf < 4; mf++)
        af[mf] = *(const f16x8*)(&lsA[cur][(wm * 64 + mf * 16 + lr) * 64 + gg * 8]);
      #pragma unroll
      for (int nf = 0; nf < NF; nf++)
        bf[nf] = *(const f16x8*)(&lsB[cur][(wn * (BN / 2) + nf * 16 + lr) * 64 + gg * 8]);
      #pragma unroll
      for (int mf = 0; mf < 4; mf++)
        #pragma unroll
        for (int nf = 0; nf < NF; nf++)
          acc[mf][nf] = MFMA16(af[mf], bf[nf], acc[mf][nf]);
    }
  }

  #pragma unroll
  for (int mf = 0; mf < 4; mf++) {
    #pragma unroll
    for (int nf = 0; nf < NF; nf++) {
      const int token = bm * BM + wm * 64 + mf * 16 + lh * 4;
      const int ch = bn * BN + wn * (BN / 2) + nf * 16 + lr;
      if constexpr (MODE == 0) {
        const int part = ch >> 9;          // 0=Q 1=K 2=V
        const int pch = ch & 511;
        if (part == 2) {
          f16x4 o;
          #pragma unroll
          for (int r = 0; r < 4; r++) o[r] = (f16)acc[mf][nf][r];
          const int bb = token >> 11, ss = token & (Sx - 1);
          const int scol = (ss & ~31) | (((ss >> 2) & 3) << 3) | (((ss >> 4) & 1) << 2);
          *(f16x4*)(O2 + ((size_t)((bb << 3) + (pch >> 6)) * 64 + (pch & 63)) * Sx + scol) = o;
        } else {
          f16* Oz = (part == 0) ? O0 : O1;
          #pragma unroll
          for (int r = 0; r < 4; r++)
            Oz[(size_t)(token + r) * Dm + pch] = (f16)acc[mf][nf][r];
        }
      } else if constexpr (MODE == 1) {
        #pragma unroll
        for (int r = 0; r < 4; r++)
          O0[(size_t)(token + r) * N + ch] = (f16)acc[mf][nf][r];
      } else if constexpr (MODE == 2) {
        #pragma unroll
        for (int r = 0; r < 4; r++) {
          float v = acc[mf][nf][r] + bias[ch];
          O0[(size_t)(token + r) * N + ch] = (f16)fmaxf(v, 0.f);
        }
      } else {
        f16* dst = O0 + (size_t)ks * NTOK * N;
        #pragma unroll
        for (int r = 0; r < 4; r++)
          dst[(size_t)(token + r) * N + ch] = (f16)acc[mf][nf][r];
      }
    }
  }
}

// ---------------------------------------------------------------- attention
// (R16 = best) Flash split-K, exp2 domain. 8 waves; grp = w>>2 handles 1024
// keys in 16 dbuf 64-key tiles (1 barrier/tile); 16 q/wave; 2-way LDS merge
// with 20-f32 slot stride. K/V XOR-swizzled via pre-swizzled global src;
// mask = MFMA C-init; row-sum via MFMA ones-trick; sigma-permuted V^T.
__global__ __launch_bounds__(512) void attn_k(
    const f16* __restrict__ q, const f16* __restrict__ kk,
    const f16* __restrict__ vt, const float* __restrict__ maskb,
    f16* __restrict__ out)
{
  __shared__ f16 lsK[2][2][64 * 64];   // [grp][dbuf]
  __shared__ f16 lsV[2][2][64 * 64];
  const int tid = threadIdx.x;
  const int l = tid & 63, w = tid >> 6;
  const int lr = l & 15, lh = l >> 4;
  const int grp = w >> 2;
  const int t256 = tid & 255;
  const int bid = blockIdx.x;
  const int nid = ((bid & 7) << 6) + (bid >> 3);   // NB=512, chunk 64
  const int bh = nid >> 5;                          // 0..15
  const int qt = nid & 31;                          // 0..31
  const int b = bh >> 3, h = bh & 7;

  const _Float16 QS = (_Float16)0.18033688f;
  f16x8 qf[2];
  #pragma unroll
  for (int s = 0; s < 2; s++) {
    size_t row = (size_t)(b * Sx + qt * 64 + (w & 3) * 16 + lr);
    f16x8 t = *(const f16x8*)(q + row * Dm + h * 64 + s * 32 + lh * 8);
    qf[s] = t * QS;
  }

  const f16x8 ones = {(f16)1, (f16)1, (f16)1, (f16)1,
                      (f16)1, (f16)1, (f16)1, (f16)1};
  f32x4 oacc[4] = {};
  f32x4 sumacc = {};
  float mrun = -1e30f;

  auto stage = [&](int t, int pb) {
    #pragma unroll
    for (int i = 0; i < 2; i++) {
      int c = i * 256 + t256, r = c >> 3, g = c & 7, gs = g ^ (r & 7);
      GLOAD_LDS16(kk + (size_t)(b * Sx + t * 64 + r) * Dm + h * 64 + gs * 8,
                  &lsK[grp][pb][c * 8]);
      GLOAD_LDS16(vt + (size_t)(bh * 64 + r) * Sx + t * 64 + gs * 8,
                  &lsV[grp][pb][c * 8]);
    }
  };
  stage(grp * 16, 0);

  for (int i = 0; i < 16; ++i) {
    const int t = grp * 16 + i;
    const int cur = i & 1;
    __syncthreads();               // vmcnt(0) drain: buf[cur] ready
    if (i < 15) stage(t + 1, cur ^ 1);

    f32x4 sacc[4];
    #pragma unroll
    for (int kf = 0; kf < 4; kf++)
      sacc[kf] = *(const f32x4*)(maskb + b * Sx + t * 64 + kf * 16 + lh * 4);
    __builtin_amdgcn_s_setprio(1);
    #pragma unroll
    for (int s = 0; s < 2; s++) {
      const int gk = (s * 4 + lh) ^ (lr & 7);
      #pragma unroll
      for (int kf = 0; kf < 4; kf++) {
        f16x8 a = *(const f16x8*)(&lsK[grp][cur][(kf * 16 + lr) * 64 + gk * 8]);
        sacc[kf] = MFMA16(a, qf[s], sacc[kf]);
      }
    }
    __builtin_amdgcn_s_setprio(0);

    float pmax;
    {
      float t0 = fmaxf(fmaxf(sacc[0][0], sacc[0][1]), sacc[0][2]);
      float t1 = fmaxf(fmaxf(sacc[0][3], sacc[1][0]), sacc[1][1]);
      float t2 = fmaxf(fmaxf(sacc[1][2], sacc[1][3]), sacc[2][0]);
      float t3 = fmaxf(fmaxf(sacc[2][1], sacc[2][2]), sacc[2][3]);
      float t4 = fmaxf(fmaxf(sacc[3][0], sacc[3][1]), sacc[3][2]);
      float u0 = fmaxf(fmaxf(t0, t1), sacc[3][3]);
      float u1 = fmaxf(fmaxf(t2, t3), t4);
      pmax = fmaxf(u0, u1);
    }
    pmax = fmaxf(pmax, __shfl_xor(pmax, 16));
    pmax = fmaxf(pmax, __shfl_xor(pmax, 32));
    if (!__all(pmax - mrun <= 8.0f)) {       // defer-max (T13)
      const float mnew = fmaxf(mrun, pmax);
      const float rs = fast_exp2(mrun - mnew);
      sumacc *= rs;
      #pragma unroll
      for (int mf = 0; mf < 4; mf++) oacc[mf] *= rs;
      mrun = mnew;
    }
    #pragma unroll
    for (int kf = 0; kf < 4; kf++)
      #pragma unroll
      for (int r = 0; r < 4; r++)
        sacc[kf][r] = fast_exp2(sacc[kf][r] - mrun);
    f16x8 pa[2];
    #pragma unroll
    for (int s = 0; s < 2; s++)
      #pragma unroll
      for (int jj = 0; jj < 8; jj++)
        pa[s][jj] = (f16)sacc[2 * s + (jj >> 2)][jj & 3];
    sumacc = MFMA16(ones, pa[0], sumacc);
    sumacc = MFMA16(ones, pa[1], sumacc);

    __builtin_amdgcn_s_setprio(1);
    #pragma unroll
    for (int s = 0; s < 2; s++) {
      const int gv = (4 * s + lh) ^ (lr & 7);
      #pragma unroll
      for (int mf = 0; mf < 4; mf++) {
        f16x8 vv = *(const f16x8*)(&lsV[grp][cur][(mf * 16 + lr) * 64 + gv * 8]);
        oacc[mf] = MFMA16(vv, pa[s], oacc[mf]);
      }
    }
    __builtin_amdgcn_s_setprio(0);
  }

  const float lrun = sumacc[0];
  __syncthreads();
  float* sO  = (float*)&lsK[0][0][0];     // 256 slots * 20 f32
  float* sML = (float*)&lsV[0][0][0];
  const int wl = (w & 3) * 64 + l;
  if (grp == 1) {
    #pragma unroll
    for (int mf = 0; mf < 4; mf++)
      #pragma unroll
      for (int r = 0; r < 4; r++) sO[wl * 20 + mf * 4 + r] = oacc[mf][r];
    sML[wl * 2] = mrun;
    sML[wl * 2 + 1] = lrun;
  }
  __syncthreads();
  if (grp == 0) {
    const float m1 = sML[wl * 2], l1 = sML[wl * 2 + 1];
    const float mm = fmaxf(mrun, m1);
    const float s0 = fast_exp2(mrun - mm), s1 = fast_exp2(m1 - mm);
    const float inv = 1.f / (lrun * s0 + l1 * s1);
    size_t row = (size_t)(b * Sx + qt * 64 + (w & 3) * 16 + lr);
    #pragma unroll
    for (int mf = 0; mf < 4; mf++) {
      f16x4 o;
      #pragma unroll
      for (int r = 0; r < 4; r++)
        o[r] = (f16)((oacc[mf][r] * s0 + sO[wl * 20 + mf * 4 + r] * s1) * inv);
      *(f16x4*)(out + row * Dm + h * 64 + mf * 16 + lh * 4) = o;
    }
  }
}

// ---------------------------------------------------------------- launch
extern "C" void kernel_launch(void* const* d_in, const int* in_sizes, int n_in,
                              void* d_out, int out_size, void* d_ws, size_t ws_size,
                              hipStream_t stream)
{
  (void)in_sizes; (void)n_in; (void)out_size; (void)ws_size;
  const int*   src  = (const int*)d_in[0];
  const float* emb  = (const float*)d_in[1];
  const float* pe   = (const float*)d_in[2];
  const float* WQ   = (const float*)d_in[3];
  const float* WK   = (const float*)d_in[4];
  const float* WV   = (const float*)d_in[5];
  const float* WO   = (const float*)d_in[6];
  const float* W1   = (const float*)d_in[7];
  const float* b1   = (const float*)d_in[8];
  const float* W2   = (const float*)d_in[9];
  const float* b2   = (const float*)d_in[10];
  const float* ln1s = (const float*)d_in[11];
  const float* ln1b = (const float*)d_in[12];
  const float* ln2s = (const float*)d_in[13];
  const float* ln2b = (const float*)d_in[14];
  const float* fns  = (const float*)d_in[15];
  const float* fnb  = (const float*)d_in[16];

  char* ws = (char*)d_ws;
  const size_t DD = (size_t)Dm * Dm;
  const size_t DQKV = (size_t)1536 * Dm;
  const size_t DF = (size_t)Dm * DFFm;
  f16* wqkv = (f16*)(ws);                      // [L][1536][512]
  f16* wtO  = wqkv + Lc * DQKV;                // [L][512][512]
  f16* wt1  = wtO + Lc * DD;                   // [L][2048][512]
  f16* wt2  = wt1 + Lc * DF;                   // [L][512][2048]
  f16* x    = wt2 + Lc * DF;                   // [4096][512] f16 residual
  f16* hbuf = x + (size_t)NTOK * Dm;
  f16* qb   = hbuf + (size_t)NTOK * Dm;
  f16* kb   = qb + (size_t)NTOK * Dm;
  f16* vtb  = kb + (size_t)NTOK * Dm;          // [16][64][2048] sigma-permuted V^T
  f16* attn = vtb + (size_t)NTOK * Dm;
  f16* aout = attn + (size_t)NTOK * Dm;        // WO result f16
  f16* ff   = aout + (size_t)NTOK * Dm;        // [4096][2048]
  f16* ffo  = ff + (size_t)NTOK * DFFm;        // W2 partials [2][4096][512]
  float* maskb = (float*)(ffo + (size_t)2 * NTOK * Dm);

  transpose_all<<<18432, dim3(32, 8), 0, stream>>>(
      WQ, WK, WV, WO, W1, W2, wqkv, wtO, wt1, wt2);
  embed_k<<<1024, 256, 0, stream>>>(src, emb, pe, ln1s, ln1b, x, hbuf, maskb);

  f16* ffo1 = ffo + (size_t)NTOK * Dm;
  for (int l = 0; l < Lc; l++) {
    const f16* wqkv_l = wqkv + (size_t)l * DQKV;
    const f16* wo = wtO + (size_t)l * DD;
    const f16* w1 = wt1 + (size_t)l * DF;
    const f16* w2 = wt2 + (size_t)l * DF;

    if (l > 0)
      lnf_k<f16, 2, 1, 1><<<1024, 256, 0, stream>>>(
          x, ffo, ffo1, b2 + (size_t)(l - 1) * Dm, ln1s + l * Dm, ln1b + l * Dm,
          hbuf, x);
    gemm_k<64, 0, 1536, 512, 1><<<768, 256, 0, stream>>>(
        hbuf, wqkv_l, qb, kb, vtb, nullptr);
    attn_k<<<512, 512, 0, stream>>>(qb, kb, vtb, maskb, attn);
    gemm_k<32, 1, 512, 512, 1><<<512, 256, 0, stream>>>(
        attn, wo, aout, nullptr, nullptr, nullptr);
    lnf_k<f16, 1, 0, 1><<<1024, 256, 0, stream>>>(
        x, aout, nullptr, nullptr, ln2s + l * Dm, ln2b + l * Dm, hbuf, x);
    gemm_k<128, 2, 2048, 512, 1><<<512, 256, 0, stream>>>(
        hbuf, w1, ff, nullptr, nullptr, b1 + (size_t)l * DFFm);
    gemm_k<64, 3, 512, 2048, 2><<<512, 256, 0, stream>>>(
        ff, w2, ffo, nullptr, nullptr, nullptr);
  }

  lnf_k<float, 2, 1, 0><<<1024, 256, 0, stream>>>(
      x, ffo, ffo1, b2 + (size_t)(Lc - 1) * Dm, fns, fnb, (float*)d_out, nullptr);
}